// Round 2
// baseline (7991.408 us; speedup 1.0000x reference)
//
#include <hip/hip_runtime.h>
#include <math.h>

// ---------------- workspace layout (bytes) ----------------
// Fixed region (43.1 MB) + chunked h1 region sized by ws_size at launch.
#define OFF_U    ((size_t)0)          // h2 then u in-place: 512*1152*8*4 = 18,874,368
#define OFF_CW   ((size_t)18874368)   // w2t (21,233,664) then c (23,592,960) — aliased
#define OFF_S    ((size_t)42467328)   // 512*10*16*4 = 327,680
#define OFF_VSUM ((size_t)42795008)   // 327,680
#define OFF_H1   ((size_t)43122688)   // Bc * 256*400*4 = Bc*409,600

// ---------------- w2 transpose: w2t[r*256+co] = w2[co*20736+r] ----------------
__global__ void transpose_w2_kernel(const float* __restrict__ w2,
                                    float* __restrict__ w2t) {
  int idx = blockIdx.x * 256 + threadIdx.x;   // idx = r*256 + co
  if (idx >= 20736 * 256) return;
  int co = idx & 255;
  int r  = idx >> 8;
  w2t[idx] = w2[(size_t)co * 20736 + r];
}

// ---------------- conv1 + relu ----------------
// x[Bc,3,28,28] -> h1[Bc,256,20,20]; grid (Bc, 64 co-groups), 256 threads
__global__ __launch_bounds__(256) void conv1_kernel(
    const float* __restrict__ x, const float* __restrict__ w1,
    const float* __restrict__ b1v, float* __restrict__ h1) {
  __shared__ float xs[2352];   // 3*28*28
  __shared__ float wsh[972];   // 4*243
  int b = blockIdx.x;
  int cobase = blockIdx.y * 4;
  int t = threadIdx.x;
  const float* xb = x + (size_t)b * 2352;
  for (int i = t; i < 2352; i += 256) xs[i] = xb[i];
  for (int i = t; i < 972; i += 256) wsh[i] = w1[(size_t)cobase * 243 + i];
  __syncthreads();
  int co_sub = t >> 6;
  int l = t & 63;
  int off[7];
  float acc[7];
#pragma unroll
  for (int k = 0; k < 7; k++) {
    int p = l + 64 * k; if (p > 399) p = 399;
    off[k] = (p / 20) * 28 + (p % 20);
    acc[k] = 0.f;
  }
  const float* wrow = &wsh[co_sub * 243];
  for (int ci = 0; ci < 3; ci++) {
#pragma unroll 3
    for (int kx = 0; kx < 9; kx++) {
#pragma unroll
      for (int ky = 0; ky < 9; ky++) {
        float wv = wrow[ci * 81 + kx * 9 + ky];
        int xoff = ci * 784 + kx * 28 + ky;
#pragma unroll
        for (int k = 0; k < 7; k++)
          acc[k] += wv * xs[off[k] + xoff];
      }
    }
  }
  int co = cobase + co_sub;
  float bv = b1v[co];
  float* out = h1 + ((size_t)b * 256 + co) * 400;
#pragma unroll
  for (int k = 0; k < 7; k++) {
    int p = l + 64 * k;
    if (p < 400) {
      float v = acc[k] + bv;
      out[p] = v > 0.f ? v : 0.f;
    }
  }
}

// ---------------- conv2 (stride 2) ----------------
// h1[Bc,256,20,20] -> h2[Bc,256,6,6]; grid (Bc, 2 co-halves), 128 threads
__global__ __launch_bounds__(128) void conv2_kernel(
    const float* __restrict__ h1, const float* __restrict__ w2t,
    const float* __restrict__ b2v, float* __restrict__ h2) {
  __shared__ float hs[400];
  int b = blockIdx.x;
  int co = blockIdx.y * 128 + threadIdx.x;
  float acc[36];
#pragma unroll
  for (int i = 0; i < 36; i++) acc[i] = 0.f;
  const float* h1b = h1 + (size_t)b * 256 * 400;
  for (int ci = 0; ci < 256; ci++) {
    __syncthreads();
    for (int i = threadIdx.x; i < 400; i += 128) hs[i] = h1b[(size_t)ci * 400 + i];
    __syncthreads();
    const float* wt = w2t + (size_t)ci * 81 * 256 + co;
#pragma unroll 1
    for (int kx = 0; kx < 9; kx++) {
      float wr[9];
#pragma unroll
      for (int ky = 0; ky < 9; ky++) wr[ky] = wt[(size_t)(kx * 9 + ky) * 256];
#pragma unroll
      for (int x = 0; x < 6; x++) {
        const float* hp = &hs[(2 * x + kx) * 20];
        float hr[19];
#pragma unroll
        for (int i = 0; i < 19; i++) hr[i] = hp[i];
#pragma unroll
        for (int y = 0; y < 6; y++) {
#pragma unroll
          for (int ky = 0; ky < 9; ky++)
            acc[x * 6 + y] += wr[ky] * hr[2 * y + ky];
        }
      }
    }
  }
  float bv = b2v[co];
  float* out = h2 + ((size_t)b * 256 + co) * 36;
#pragma unroll
  for (int i = 0; i < 36; i++) out[i] = acc[i] + bv;
}

// ---------------- squash over groups of 8, IN PLACE (primary capsules) ----------------
__global__ void squash_u_kernel(float* __restrict__ hu) {
  int g = blockIdx.x * 256 + threadIdx.x;   // 512*1152 groups
  if (g >= 512 * 1152) return;
  float4* p = (float4*)(hu + (size_t)g * 8);
  float4 a = p[0], bq = p[1];
  float sn = a.x*a.x + a.y*a.y + a.z*a.z + a.w*a.w +
             bq.x*bq.x + bq.y*bq.y + bq.z*bq.z + bq.w*bq.w;
  float scale = sn / (1.f + sn) / (sqrtf(sn) + 1e-6f);
  a.x *= scale; a.y *= scale; a.z *= scale; a.w *= scale;
  bq.x *= scale; bq.y *= scale; bq.z *= scale; bq.w *= scale;
  p[0] = a; p[1] = bq;
}

// ---------------- s[b,o,e] = sum_n c[b,n,o] * (sum_d u[b,n,d] W[n,o,d,e]) ----------------
// u_hat recomputed on the fly. c == nullptr -> uniform 0.1 (iteration 0).
// grid: 256 blocks (pairs of b), 320 threads: t<160 -> b0, t>=160 -> b1; (o,e) = (r/16, r%16)
__global__ __launch_bounds__(320) void s_kernel(
    const float* __restrict__ u, const float* __restrict__ W,
    const float* __restrict__ c, float* __restrict__ s) {
  __shared__ float Wl[4 * 1360];   // 4 n's, per-n layout o*136 + d*16 + e (pad 136 kills 4-way banks)
  __shared__ float ul[4][2][8];
  __shared__ float cl[4][2][10];
  int b0 = blockIdx.x * 2;
  int t = threadIdx.x;
  int sub = t / 160;        // which b of the pair
  int r = t % 160;
  int o = r >> 4;
  int e = r & 15;
  float acc = 0.f;
  for (int nc = 0; nc < 1152; nc += 4) {
    __syncthreads();
    for (int idx = t; idx < 5120; idx += 320) {
      int nn = idx >> 10;            // idx / 1280... careful: 1280 not pow2
      nn = idx / 1280;
      int rem = idx - nn * 1280;
      int oo = rem >> 7;             // rem / 128
      int de = rem & 127;
      Wl[nn * 1360 + oo * 136 + de] = W[(size_t)(nc + nn) * 1280 + rem];
    }
    if (t < 64) {
      int nn = t >> 4, r2 = t & 15, bb = r2 >> 3, dd = r2 & 7;
      ul[nn][bb][dd] = u[((size_t)(b0 + bb) * 1152 + nc + nn) * 8 + dd];
    }
    if (c != nullptr && t < 80) {
      int nn = t / 20, r2 = t % 20, bb = r2 / 10, oo = r2 % 10;
      cl[nn][bb][oo] = c[((size_t)(b0 + bb) * 1152 + nc + nn) * 10 + oo];
    }
    __syncthreads();
#pragma unroll
    for (int nn = 0; nn < 4; nn++) {
      const float* wp = &Wl[nn * 1360 + o * 136 + e];
      float uh = 0.f;
#pragma unroll
      for (int d = 0; d < 8; d++) uh = fmaf(ul[nn][sub][d], wp[d * 16], uh);
      float cv = (c != nullptr) ? cl[nn][sub][o] : 1.f;
      acc = fmaf(cv, uh, acc);
    }
  }
  if (c == nullptr) acc *= 0.1f;
  s[(size_t)(b0 + sub) * 160 + r] = acc;
}

// ---------------- v = squash(s); dst = v or dst += v; dst may be d_out ----------------
__global__ void squash_v_kernel(const float* __restrict__ s,
                                float* __restrict__ dst, int accumulate) {
  int g = blockIdx.x * 256 + threadIdx.x;   // 5120 groups of 16
  if (g >= 5120) return;
  const float* p = s + (size_t)g * 16;
  float r[16];
  float sn = 0.f;
#pragma unroll
  for (int e = 0; e < 16; e++) { r[e] = p[e]; sn += r[e] * r[e]; }
  float scale = sn / (1.f + sn) / (sqrtf(sn) + 1e-6f);
  float* q = dst + (size_t)g * 16;
#pragma unroll
  for (int e = 0; e < 16; e++) {
    float val = r[e] * scale;
    q[e] = accumulate ? (q[e] + val) : val;
  }
}

// ---------------- logits (on-the-fly u_hat . vsum) + softmax -> c ----------------
// b_t[b,n,o] = sum_e (sum_d u[b,n,d] W[n,o,d,e]) * vsum[b,o,e]; c = softmax_o
// grid (1152 n, 2 b-halves), 256 threads (thread = one b)
__global__ __launch_bounds__(256) void logits_c_kernel(
    const float* __restrict__ u, const float* __restrict__ W,
    const float* __restrict__ vsum, float* __restrict__ c) {
  __shared__ float Wl[1280];
  int n = blockIdx.x;
  int t = threadIdx.x;
  int b = blockIdx.y * 256 + t;
  for (int i = t; i < 1280; i += 256) Wl[i] = W[(size_t)n * 1280 + i];
  __syncthreads();
  float uu[8];
  const float* up = u + ((size_t)b * 1152 + n) * 8;
#pragma unroll
  for (int d = 0; d < 8; d++) uu[d] = up[d];
  const float* vp = vsum + (size_t)b * 160;
  float l[10];
#pragma unroll 1
  for (int o = 0; o < 10; o++) {
    float dot = 0.f;
#pragma unroll
    for (int e = 0; e < 16; e++) {
      float uh = 0.f;
#pragma unroll
      for (int d = 0; d < 8; d++) uh = fmaf(uu[d], Wl[o * 128 + d * 16 + e], uh);
      dot = fmaf(uh, vp[o * 16 + e], dot);
    }
    l[o] = dot;
  }
  float m = l[0];
#pragma unroll
  for (int o = 1; o < 10; o++) m = fmaxf(m, l[o]);
  float sum = 0.f;
#pragma unroll
  for (int o = 0; o < 10; o++) { l[o] = expf(l[o] - m); sum += l[o]; }
  float inv = 1.f / sum;
  float* cp = c + ((size_t)b * 1152 + n) * 10;
#pragma unroll
  for (int o = 0; o < 10; o++) cp[o] = l[o] * inv;
}

extern "C" void kernel_launch(void* const* d_in, const int* in_sizes, int n_in,
                              void* d_out, int out_size, void* d_ws, size_t ws_size,
                              hipStream_t stream) {
  const float* x   = (const float*)d_in[0];   // [512,3,28,28]
  const float* w1  = (const float*)d_in[1];   // [256,3,9,9]
  const float* b1v = (const float*)d_in[2];   // [256]
  const float* w2  = (const float*)d_in[3];   // [256,256,9,9]
  const float* b2v = (const float*)d_in[4];   // [256]
  const float* W   = (const float*)d_in[5];   // [1152,10,8,16] flat
  float* out = (float*)d_out;                 // [512,10,16] fp32

  char* ws = (char*)d_ws;
  float* u    = (float*)(ws + OFF_U);      // h2 written here, squashed in place -> u
  float* cw   = (float*)(ws + OFF_CW);     // w2t during conv, c during routing
  float* s    = (float*)(ws + OFF_S);
  float* vsum = (float*)(ws + OFF_VSUM);
  float* h1   = (float*)(ws + OFF_H1);

  // batch chunk size for the conv stage, sized to the workspace we actually have
  int Bc = 512;
  while (Bc > 8 && OFF_H1 + (size_t)Bc * 409600 > ws_size) Bc >>= 1;

  // conv2 weight transpose (into cw region; dead before c is first written)
  transpose_w2_kernel<<<20736, 256, 0, stream>>>(w2, cw);

  for (int b0 = 0; b0 < 512; b0 += Bc) {
    conv1_kernel<<<dim3(Bc, 64), 256, 0, stream>>>(x + (size_t)b0 * 2352, w1, b1v, h1);
    conv2_kernel<<<dim3(Bc, 2), 128, 0, stream>>>(h1, cw, b2v, u + (size_t)b0 * 9216);
  }
  // primary-capsule squash in place: h2 -> u
  squash_u_kernel<<<2304, 256, 0, stream>>>(u);

  // iter 0: uniform c -> s0; vsum = v0
  s_kernel<<<256, 320, 0, stream>>>(u, W, nullptr, s);
  squash_v_kernel<<<20, 256, 0, stream>>>(s, vsum, 0);
  // iter 1: logits from vsum(=v0) -> c -> s1; vsum += v1
  logits_c_kernel<<<dim3(1152, 2), 256, 0, stream>>>(u, W, vsum, cw);
  s_kernel<<<256, 320, 0, stream>>>(u, W, cw, s);
  squash_v_kernel<<<20, 256, 0, stream>>>(s, vsum, 1);
  // iter 2: logits from vsum(=v0+v1) -> c -> s2; out = squash(s2)
  logits_c_kernel<<<dim3(1152, 2), 256, 0, stream>>>(u, W, vsum, cw);
  s_kernel<<<256, 320, 0, stream>>>(u, W, cw, s);
  squash_v_kernel<<<20, 256, 0, stream>>>(s, out, 0);
}

// Round 3
// 3308.125 us; speedup vs baseline: 2.4157x; 2.4157x over previous
//
#include <hip/hip_runtime.h>
#include <math.h>

typedef short short4v __attribute__((ext_vector_type(4)));
typedef short short8v __attribute__((ext_vector_type(8)));
typedef float float4v __attribute__((ext_vector_type(4)));

// ---------------- workspace layout (bytes) ----------------
#define OFF_U    ((size_t)0)          // h2 then u in-place: 512*1152*8*4 = 18,874,368
#define OFF_CW   ((size_t)18874368)   // w2b bf16 (10,616,832) then c fp32 (23,592,960) — aliased
#define OFF_S    ((size_t)42467328)   // 512*10*16*4 = 327,680
#define OFF_VSUM ((size_t)42795008)   // 327,680 (end 43,122,688)

__device__ inline short f2bf(float f) {
  union { float f; unsigned u; } v; v.f = f;
  unsigned r = v.u + 0x7FFFu + ((v.u >> 16) & 1u);
  return (short)(r >> 16);
}
__device__ inline float bf2f(short s) {
  union { unsigned u; float f; } v; v.u = ((unsigned)(unsigned short)s) << 16;
  return v.f;
}

// ---------------- w2 [co][ci][81] fp32 -> w2b [tap][co][ci] bf16 ----------------
__global__ __launch_bounds__(256) void transpose_w2b_kernel(
    const float* __restrict__ w2, short* __restrict__ w2b) {
  __shared__ short tl[81][66];
  int co = blockIdx.x >> 2, ci0 = (blockIdx.x & 3) * 64;
  for (int f = threadIdx.x; f < 64 * 81; f += 256) {
    int cip = f / 81, tap = f % 81;
    tl[tap][cip] = f2bf(w2[((size_t)co * 256 + ci0 + cip) * 81 + tap]);
  }
  __syncthreads();
  for (int f = threadIdx.x; f < 81 * 64; f += 256) {
    int tap = f >> 6, cip = f & 63;
    w2b[((size_t)tap * 256 + co) * 256 + ci0 + cip] = tl[tap][cip];
  }
}

// ---------------- fused conv1+relu+conv2 (bf16 MFMA implicit GEMM) ----------------
// grid 256 blocks (2 batches each), 256 threads (4 waves).
// Per ci-chunk of 32: conv1 -> h1l LDS tile [2b][400pos][32ci+4pad] bf16,
// then 81 taps x 1 Kstep MFMA: C[m=(bb,x,y) pad80][n=co 256] += A*B.
__global__ __launch_bounds__(256, 2) void conv_fused_kernel(
    const float* __restrict__ x, const float* __restrict__ w1,
    const float* __restrict__ b1v, const short* __restrict__ w2b,
    const float* __restrict__ b2v, float* __restrict__ h2) {
  __shared__ short xs[2][2352];      // x for 2 batches, bf16
  __shared__ short w1s[16][244];     // conv1 weights, 16 ci at a time, bf16
  __shared__ short h1l[2 * 400 * 36]; // h1 tile: [bb][pos][ci 0..31, pad to 36]

  int b0 = blockIdx.x * 2;
  int t = threadIdx.x;
  int lane = t & 63;
  int wv = t >> 6;            // wave 0..3 -> co range wv*64
  int l15 = lane & 15, lq = lane >> 4;

  // stage x as bf16
  for (int i = t; i < 2 * 2352; i += 256) {
    int bb = i / 2352, j = i - bb * 2352;
    xs[bb][j] = f2bf(x[(size_t)(b0 + bb) * 2352 + j]);
  }

  // accumulators: 5 Mtiles x 4 Ntiles of 16x16
  float4v acc[5][4];
#pragma unroll
  for (int mt = 0; mt < 5; mt++)
#pragma unroll
    for (int nt = 0; nt < 4; nt++) acc[mt][nt] = (float4v){0.f, 0.f, 0.f, 0.f};

  // per-lane A-row mapping (m = mt*16 + l15)
  int abb[5], apx[5], apy[5];
#pragma unroll
  for (int mt = 0; mt < 5; mt++) {
    int m = mt * 16 + l15;
    int bb = m / 40, s = m % 40;
    if (s >= 36) s = 0;       // pad rows read row 0 (valid data, discarded at store)
    abb[mt] = bb; apx[mt] = (s / 6) * 2; apy[mt] = (s % 6) * 2;
  }
  int co[4];
#pragma unroll
  for (int nt = 0; nt < 4; nt++) co[nt] = wv * 64 + nt * 16 + l15;

  int cii = t >> 4, pg = t & 15;

  for (int ch = 0; ch < 8; ch++) {
    int ci0 = ch * 32;
    // ---- conv1 phase: two halves of 16 ci ----
    for (int p = 0; p < 2; p++) {
      __syncthreads();   // prev MFMA / prev conv1 done with h1l & w1s
      for (int i = t; i < 16 * 243; i += 256) {
        int cc = i / 243, tp = i - cc * 243;
        w1s[cc][tp] = f2bf(w1[(size_t)(ci0 + p * 16 + cc) * 243 + tp]);
      }
      __syncthreads();
      int ciG = ci0 + p * 16 + cii;
      float bias1 = b1v[ciG];
      int cLoc = p * 16 + cii;
      for (int px = pg; px < 20; px += 16) {
        for (int bb = 0; bb < 2; bb++) {
          float a20[20];
#pragma unroll
          for (int py = 0; py < 20; py++) a20[py] = 0.f;
#pragma unroll 1
          for (int cin = 0; cin < 3; cin++) {
#pragma unroll 1
            for (int kx = 0; kx < 9; kx++) {
              float r[28];
              const uint2* xp = (const uint2*)&xs[bb][cin * 784 + (px + kx) * 28];
#pragma unroll
              for (int q = 0; q < 7; q++) {
                uint2 u2 = xp[q];
                union { unsigned u; float f; } c0, c1, c2, c3;
                c0.u = u2.x << 16; c1.u = u2.x & 0xFFFF0000u;
                c2.u = u2.y << 16; c3.u = u2.y & 0xFFFF0000u;
                r[4 * q] = c0.f; r[4 * q + 1] = c1.f;
                r[4 * q + 2] = c2.f; r[4 * q + 3] = c3.f;
              }
              const short* wrow = &w1s[cii][cin * 81 + kx * 9];
#pragma unroll
              for (int ky = 0; ky < 9; ky++) {
                float wv1 = bf2f(wrow[ky]);
#pragma unroll
                for (int py = 0; py < 20; py++)
                  a20[py] = fmaf(wv1, r[py + ky], a20[py]);
              }
            }
          }
#pragma unroll
          for (int py = 0; py < 20; py++) {
            float h = a20[py] + bias1;
            h1l[(bb * 400 + px * 20 + py) * 36 + cLoc] = f2bf(h > 0.f ? h : 0.f);
          }
        }
      }
    }
    __syncthreads();   // h1l complete
    // ---- MFMA phase: 81 taps, K=32 each ----
    short8v bcur[4], bnxt[4];
#pragma unroll
    for (int nt = 0; nt < 4; nt++)
      bcur[nt] = *(const short8v*)(w2b + (size_t)co[nt] * 256 + lq * 8 + ci0);
#pragma unroll 1
    for (int tap = 0; tap < 81; tap++) {
      int kx = tap / 9, ky = tap - 9 * kx;
      int tn = (tap < 80) ? tap + 1 : 80;
#pragma unroll
      for (int nt = 0; nt < 4; nt++)
        bnxt[nt] = *(const short8v*)(w2b + (size_t)tn * 65536 +
                                     (size_t)co[nt] * 256 + lq * 8 + ci0);
      short8v af[5];
#pragma unroll
      for (int mt = 0; mt < 5; mt++) {
        int pos = (apx[mt] + kx) * 20 + apy[mt] + ky;
        const short4v* ap = (const short4v*)&h1l[(abb[mt] * 400 + pos) * 36 + lq * 8];
        short4v lo = ap[0], hi = ap[1];
        short8v a;
        a[0] = lo[0]; a[1] = lo[1]; a[2] = lo[2]; a[3] = lo[3];
        a[4] = hi[0]; a[5] = hi[1]; a[6] = hi[2]; a[7] = hi[3];
        af[mt] = a;
      }
#pragma unroll
      for (int mt = 0; mt < 5; mt++)
#pragma unroll
        for (int nt = 0; nt < 4; nt++)
          acc[mt][nt] = __builtin_amdgcn_mfma_f32_16x16x32_bf16(
              af[mt], bcur[nt], acc[mt][nt], 0, 0, 0);
#pragma unroll
      for (int nt = 0; nt < 4; nt++) bcur[nt] = bnxt[nt];
    }
  }
  // ---- epilogue: bias + store h2[b][co][s] ----
#pragma unroll
  for (int nt = 0; nt < 4; nt++) {
    float bias = b2v[co[nt]];
#pragma unroll
    for (int mt = 0; mt < 5; mt++) {
#pragma unroll
      for (int r4 = 0; r4 < 4; r4++) {
        int m = mt * 16 + lq * 4 + r4;
        int bb = m / 40, s = m % 40;
        if (s < 36)
          h2[((size_t)(b0 + bb) * 256 + co[nt]) * 36 + s] = acc[mt][nt][r4] + bias;
      }
    }
  }
}

// ---------------- squash over groups of 8, IN PLACE (primary capsules) ----------------
__global__ void squash_u_kernel(float* __restrict__ hu) {
  int g = blockIdx.x * 256 + threadIdx.x;   // 512*1152 groups
  if (g >= 512 * 1152) return;
  float4* p = (float4*)(hu + (size_t)g * 8);
  float4 a = p[0], bq = p[1];
  float sn = a.x*a.x + a.y*a.y + a.z*a.z + a.w*a.w +
             bq.x*bq.x + bq.y*bq.y + bq.z*bq.z + bq.w*bq.w;
  float scale = sn / (1.f + sn) / (sqrtf(sn) + 1e-6f);
  a.x *= scale; a.y *= scale; a.z *= scale; a.w *= scale;
  bq.x *= scale; bq.y *= scale; bq.z *= scale; bq.w *= scale;
  p[0] = a; p[1] = bq;
}

// ---------------- s[b,o,e] = sum_n c[b,n,o] * (sum_d u[b,n,d] W[n,o,d,e]) ----------------
__global__ __launch_bounds__(320) void s_kernel(
    const float* __restrict__ u, const float* __restrict__ W,
    const float* __restrict__ c, float* __restrict__ s) {
  __shared__ float Wl[4 * 1360];   // 4 n's, per-n layout o*136 + d*16 + e
  __shared__ float ul[4][2][8];
  __shared__ float cl[4][2][10];
  int b0 = blockIdx.x * 2;
  int t = threadIdx.x;
  int sub = t / 160;
  int r = t % 160;
  int o = r >> 4;
  int e = r & 15;
  float acc = 0.f;
  for (int nc = 0; nc < 1152; nc += 4) {
    __syncthreads();
    for (int idx = t; idx < 5120; idx += 320) {
      int nn = idx / 1280;
      int rem = idx - nn * 1280;
      int oo = rem >> 7;
      int de = rem & 127;
      Wl[nn * 1360 + oo * 136 + de] = W[(size_t)(nc + nn) * 1280 + rem];
    }
    if (t < 64) {
      int nn = t >> 4, r2 = t & 15, bb = r2 >> 3, dd = r2 & 7;
      ul[nn][bb][dd] = u[((size_t)(b0 + bb) * 1152 + nc + nn) * 8 + dd];
    }
    if (c != nullptr && t < 80) {
      int nn = t / 20, r2 = t % 20, bb = r2 / 10, oo = r2 % 10;
      cl[nn][bb][oo] = c[((size_t)(b0 + bb) * 1152 + nc + nn) * 10 + oo];
    }
    __syncthreads();
#pragma unroll
    for (int nn = 0; nn < 4; nn++) {
      const float* wp = &Wl[nn * 1360 + o * 136 + e];
      float uh = 0.f;
#pragma unroll
      for (int d = 0; d < 8; d++) uh = fmaf(ul[nn][sub][d], wp[d * 16], uh);
      float cv = (c != nullptr) ? cl[nn][sub][o] : 1.f;
      acc = fmaf(cv, uh, acc);
    }
  }
  if (c == nullptr) acc *= 0.1f;
  s[(size_t)(b0 + sub) * 160 + r] = acc;
}

// ---------------- v = squash(s); dst = v or dst += v ----------------
__global__ void squash_v_kernel(const float* __restrict__ s,
                                float* __restrict__ dst, int accumulate) {
  int g = blockIdx.x * 256 + threadIdx.x;   // 5120 groups of 16
  if (g >= 5120) return;
  const float* p = s + (size_t)g * 16;
  float r[16];
  float sn = 0.f;
#pragma unroll
  for (int e = 0; e < 16; e++) { r[e] = p[e]; sn += r[e] * r[e]; }
  float scale = sn / (1.f + sn) / (sqrtf(sn) + 1e-6f);
  float* q = dst + (size_t)g * 16;
#pragma unroll
  for (int e = 0; e < 16; e++) {
    float val = r[e] * scale;
    q[e] = accumulate ? (q[e] + val) : val;
  }
}

// ---------------- logits (on-the-fly u_hat . vsum) + softmax -> c ----------------
__global__ __launch_bounds__(256) void logits_c_kernel(
    const float* __restrict__ u, const float* __restrict__ W,
    const float* __restrict__ vsum, float* __restrict__ c) {
  __shared__ float Wl[1280];
  int n = blockIdx.x;
  int t = threadIdx.x;
  int b = blockIdx.y * 256 + t;
  for (int i = t; i < 1280; i += 256) Wl[i] = W[(size_t)n * 1280 + i];
  __syncthreads();
  float uu[8];
  const float* up = u + ((size_t)b * 1152 + n) * 8;
#pragma unroll
  for (int d = 0; d < 8; d++) uu[d] = up[d];
  const float* vp = vsum + (size_t)b * 160;
  float l[10];
#pragma unroll 1
  for (int o = 0; o < 10; o++) {
    float dot = 0.f;
#pragma unroll
    for (int e = 0; e < 16; e++) {
      float uh = 0.f;
#pragma unroll
      for (int d = 0; d < 8; d++) uh = fmaf(uu[d], Wl[o * 128 + d * 16 + e], uh);
      dot = fmaf(uh, vp[o * 16 + e], dot);
    }
    l[o] = dot;
  }
  float m = l[0];
#pragma unroll
  for (int o = 1; o < 10; o++) m = fmaxf(m, l[o]);
  float sum = 0.f;
#pragma unroll
  for (int o = 0; o < 10; o++) { l[o] = expf(l[o] - m); sum += l[o]; }
  float inv = 1.f / sum;
  float* cp = c + ((size_t)b * 1152 + n) * 10;
#pragma unroll
  for (int o = 0; o < 10; o++) cp[o] = l[o] * inv;
}

extern "C" void kernel_launch(void* const* d_in, const int* in_sizes, int n_in,
                              void* d_out, int out_size, void* d_ws, size_t ws_size,
                              hipStream_t stream) {
  const float* x   = (const float*)d_in[0];   // [512,3,28,28]
  const float* w1  = (const float*)d_in[1];   // [256,3,9,9]
  const float* b1v = (const float*)d_in[2];   // [256]
  const float* w2  = (const float*)d_in[3];   // [256,256,9,9]
  const float* b2v = (const float*)d_in[4];   // [256]
  const float* W   = (const float*)d_in[5];   // [1152,10,8,16] flat
  float* out = (float*)d_out;                 // [512,10,16] fp32

  char* ws = (char*)d_ws;
  float* u    = (float*)(ws + OFF_U);      // h2 written here, squashed in place
  short* w2b  = (short*)(ws + OFF_CW);     // bf16 transposed conv2 weights
  float* c    = (float*)(ws + OFF_CW);     // routing coefficients (aliases w2b, dead by then)
  float* s    = (float*)(ws + OFF_S);
  float* vsum = (float*)(ws + OFF_VSUM);

  // 1. weights -> [tap][co][ci] bf16
  transpose_w2b_kernel<<<1024, 256, 0, stream>>>(w2, w2b);
  // 2. fused conv1+relu+conv2 (full batch, one dispatch)
  conv_fused_kernel<<<256, 256, 0, stream>>>(x, w1, b1v, w2b, b2v, u);
  // 3. primary-capsule squash in place
  squash_u_kernel<<<2304, 256, 0, stream>>>(u);
  // 4. iter 0: uniform c -> s0; vsum = v0
  s_kernel<<<256, 320, 0, stream>>>(u, W, nullptr, s);
  squash_v_kernel<<<20, 256, 0, stream>>>(s, vsum, 0);
  // 5. iter 1
  logits_c_kernel<<<dim3(1152, 2), 256, 0, stream>>>(u, W, vsum, c);
  s_kernel<<<256, 320, 0, stream>>>(u, W, c, s);
  squash_v_kernel<<<20, 256, 0, stream>>>(s, vsum, 1);
  // 6. iter 2 -> output
  logits_c_kernel<<<dim3(1152, 2), 256, 0, stream>>>(u, W, vsum, c);
  s_kernel<<<256, 320, 0, stream>>>(u, W, c, s);
  squash_v_kernel<<<20, 256, 0, stream>>>(s, out, 0);
}

// Round 4
// 1443.186 us; speedup vs baseline: 5.5373x; 2.2922x over previous
//
#include <hip/hip_runtime.h>
#include <math.h>

typedef short short4v __attribute__((ext_vector_type(4)));
typedef short short8v __attribute__((ext_vector_type(8)));
typedef float float4v __attribute__((ext_vector_type(4)));
typedef unsigned int uint4u __attribute__((ext_vector_type(4), aligned(4)));

// ---------------- workspace layout (bytes) ----------------
#define OFF_U     ((size_t)0)          // h2 then u in-place: 512*1152*8*4 = 18,874,368
#define OFF_A     ((size_t)18874368)   // union{ w2b bf16 10.6MB | cb bf16 11.8MB } -> 11,796,480
#define OFF_WT    ((size_t)30670848)   // Wt fp32 [n][o][e][d]: 5,898,240
#define OFF_SPART ((size_t)36569088)   // [8][512][160] f32 = 2,621,440
#define OFF_VSUM  ((size_t)39190528)   // 327,680 (end 39,518,208)

__device__ inline short f2bf(float f) {
  union { float f; unsigned u; } v; v.f = f;
  unsigned r = v.u + 0x7FFFu + ((v.u >> 16) & 1u);
  return (short)(r >> 16);
}
__device__ inline float bf2f_lo(unsigned u) {
  union { unsigned u; float f; } v; v.u = u << 16; return v.f;
}
__device__ inline float bf2f_hi(unsigned u) {
  union { unsigned u; float f; } v; v.u = u & 0xFFFF0000u; return v.f;
}

// ---------------- w2 [co][ci][81] fp32 -> w2b [tap][co][ci] bf16 ----------------
__global__ __launch_bounds__(256) void transpose_w2b_kernel(
    const float* __restrict__ w2, short* __restrict__ w2b) {
  __shared__ short tl[81][66];
  int co = blockIdx.x >> 2, ci0 = (blockIdx.x & 3) * 64;
  for (int f = threadIdx.x; f < 64 * 81; f += 256) {
    int cip = f / 81, tap = f % 81;
    tl[tap][cip] = f2bf(w2[((size_t)co * 256 + ci0 + cip) * 81 + tap]);
  }
  __syncthreads();
  for (int f = threadIdx.x; f < 81 * 64; f += 256) {
    int tap = f >> 6, cip = f & 63;
    w2b[((size_t)tap * 256 + co) * 256 + ci0 + cip] = tl[tap][cip];
  }
}

// ---------------- W [n][o][d][e] -> Wt [n][o][e][d] fp32 ----------------
__global__ __launch_bounds__(256) void prep_wt_kernel(
    const float* __restrict__ W, float* __restrict__ Wt) {
  int idx = blockIdx.x * 256 + threadIdx.x;   // 1152*1280 = 1,474,560
  if (idx >= 1152 * 1280) return;
  int n = idx / 1280, r = idx - n * 1280;
  int o = r >> 7, de = r & 127;
  int d = de >> 4, e = de & 15;
  Wt[(((size_t)n * 10 + o) * 16 + e) * 8 + d] = W[idx];
}

// ---------------- fused conv1+relu+conv2 (bf16 MFMA implicit GEMM) ----------------
// grid 256 blocks (2 batches each), 256 threads (4 waves).
__global__ __launch_bounds__(256) void conv_fused_kernel(
    const float* __restrict__ x, const float* __restrict__ w1,
    const float* __restrict__ b1v, const short* __restrict__ w2b,
    const float* __restrict__ b2v, float* __restrict__ h2) {
  __shared__ float xs[2][2352];       // x fp32, 2 batches (18.8 KB)
  __shared__ float w1s[32][259];      // conv1 weights fp32, 32 ci (33.2 KB; 259 kills conflicts)
  __shared__ short h1l[2 * 400 * 36]; // h1 tile bf16: [bb][pos][ci 0..31, pad 36] (57.6 KB)

  int b0 = blockIdx.x * 2;
  int t = threadIdx.x;
  int lane = t & 63;
  int wv = t >> 6;
  int l15 = lane & 15, lq = lane >> 4;

  for (int i = t; i < 2 * 2352; i += 256) {
    int bb = i / 2352, j = i - bb * 2352;
    xs[bb][j] = x[(size_t)(b0 + bb) * 2352 + j];
  }

  float4v acc[5][4];
#pragma unroll
  for (int mt = 0; mt < 5; mt++)
#pragma unroll
    for (int nt = 0; nt < 4; nt++) acc[mt][nt] = (float4v){0.f, 0.f, 0.f, 0.f};

  int abb[5], apx[5], apy[5];
#pragma unroll
  for (int mt = 0; mt < 5; mt++) {
    int m = mt * 16 + l15;
    int bb = m / 40, s = m % 40;
    if (s >= 36) s = 0;
    abb[mt] = bb; apx[mt] = (s / 6) * 2; apy[mt] = (s % 6) * 2;
  }
  int co[4];
#pragma unroll
  for (int nt = 0; nt < 4; nt++) co[nt] = wv * 64 + nt * 16 + l15;

  int cii = t & 31;      // ci within chunk (contiguous lanes -> conflict-free h1l writes)
  int pg = t >> 5;       // 0..7 work-group index over (bb,px) units

  for (int ch = 0; ch < 8; ch++) {
    int ci0 = ch * 32;
    __syncthreads();   // prev MFMA done with h1l; w1s reusable
    // stage conv1 weights for the whole 32-ci chunk
    for (int i = t; i < 32 * 243; i += 256) {
      int cc = i / 243, tp = i - cc * 243;
      w1s[cc][tp] = w1[(size_t)(ci0 + cc) * 243 + tp];
    }
    __syncthreads();
    // ---- conv1: 40 (bb,px) units split 5 per pg ----
    float bias1 = b1v[ci0 + cii];
#pragma unroll 1
    for (int un = pg; un < 40; un += 8) {
      int bb = un / 20, px = un % 20;
      float a20[20];
#pragma unroll
      for (int py = 0; py < 20; py++) a20[py] = 0.f;
#pragma unroll 1
      for (int cin = 0; cin < 3; cin++) {
#pragma unroll 1
        for (int kx = 0; kx < 9; kx++) {
          float r[28];
          const float4* xp = (const float4*)&xs[bb][cin * 784 + (px + kx) * 28];
#pragma unroll
          for (int q = 0; q < 7; q++) {
            float4 f4 = xp[q];
            r[4 * q] = f4.x; r[4 * q + 1] = f4.y;
            r[4 * q + 2] = f4.z; r[4 * q + 3] = f4.w;
          }
          const float* wrow = &w1s[cii][cin * 81 + kx * 9];
#pragma unroll
          for (int ky = 0; ky < 9; ky++) {
            float wv1 = wrow[ky];
#pragma unroll
            for (int py = 0; py < 20; py++)
              a20[py] = fmaf(wv1, r[py + ky], a20[py]);
          }
        }
      }
#pragma unroll
      for (int py = 0; py < 20; py++) {
        float h = a20[py] + bias1;
        h1l[(bb * 400 + px * 20 + py) * 36 + cii] = f2bf(h > 0.f ? h : 0.f);
      }
    }
    __syncthreads();   // h1l ready
    // ---- MFMA phase: 81 taps, K=32 each ----
    short8v bcur[4], bnxt[4];
#pragma unroll
    for (int nt = 0; nt < 4; nt++)
      bcur[nt] = *(const short8v*)(w2b + (size_t)co[nt] * 256 + lq * 8 + ci0);
#pragma unroll 1
    for (int tap = 0; tap < 81; tap++) {
      int kx = tap / 9, ky = tap - 9 * kx;
      int tn = (tap < 80) ? tap + 1 : 80;
#pragma unroll
      for (int nt = 0; nt < 4; nt++)
        bnxt[nt] = *(const short8v*)(w2b + (size_t)tn * 65536 +
                                     (size_t)co[nt] * 256 + lq * 8 + ci0);
      short8v af[5];
#pragma unroll
      for (int mt = 0; mt < 5; mt++) {
        int pos = (apx[mt] + kx) * 20 + apy[mt] + ky;
        const short4v* ap = (const short4v*)&h1l[(abb[mt] * 400 + pos) * 36 + lq * 8];
        short4v lo = ap[0], hi = ap[1];
        af[mt] = __builtin_shufflevector(lo, hi, 0, 1, 2, 3, 4, 5, 6, 7);
      }
#pragma unroll
      for (int mt = 0; mt < 5; mt++)
#pragma unroll
        for (int nt = 0; nt < 4; nt++)
          acc[mt][nt] = __builtin_amdgcn_mfma_f32_16x16x32_bf16(
              af[mt], bcur[nt], acc[mt][nt], 0, 0, 0);
#pragma unroll
      for (int nt = 0; nt < 4; nt++) bcur[nt] = bnxt[nt];
    }
  }
  // ---- epilogue ----
#pragma unroll
  for (int nt = 0; nt < 4; nt++) {
    float bias = b2v[co[nt]];
#pragma unroll
    for (int mt = 0; mt < 5; mt++) {
#pragma unroll
      for (int r4 = 0; r4 < 4; r4++) {
        int m = mt * 16 + lq * 4 + r4;
        int bb = m / 40, s = m % 40;
        if (s < 36)
          h2[((size_t)(b0 + bb) * 256 + co[nt]) * 36 + s] = acc[mt][nt][r4] + bias;
      }
    }
  }
}

// ---------------- squash over groups of 8, IN PLACE ----------------
__global__ void squash_u_kernel(float* __restrict__ hu) {
  int g = blockIdx.x * 256 + threadIdx.x;   // 512*1152 groups
  if (g >= 512 * 1152) return;
  float4* p = (float4*)(hu + (size_t)g * 8);
  float4 a = p[0], bq = p[1];
  float sn = a.x*a.x + a.y*a.y + a.z*a.z + a.w*a.w +
             bq.x*bq.x + bq.y*bq.y + bq.z*bq.z + bq.w*bq.w;
  float scale = sn / (1.f + sn) / (sqrtf(sn) + 1e-6f);
  a.x *= scale; a.y *= scale; a.z *= scale; a.w *= scale;
  bq.x *= scale; bq.y *= scale; bq.z *= scale; bq.w *= scale;
  p[0] = a; p[1] = bq;
}

// ---------------- s partials: thread=(b,e), acc[o], no LDS ----------------
// grid (32 b-tiles, 8 n-chunks), 256 threads. cb==nullptr -> uniform routing.
__global__ __launch_bounds__(256) void s_part_kernel(
    const float* __restrict__ u, const float* __restrict__ Wt,
    const short* __restrict__ cb, float* __restrict__ spart) {
  int bt = blockIdx.x, nc = blockIdx.y;
  int t = threadIdx.x;
  int bq = t >> 4, e = t & 15;
  int b = bt * 16 + bq;
  float acc[10];
#pragma unroll
  for (int o = 0; o < 10; o++) acc[o] = 0.f;
  int n0 = nc * 144;
#pragma unroll 1
  for (int n = n0; n < n0 + 144; n++) {
    const float4* up = (const float4*)(u + ((size_t)b * 1152 + n) * 8);
    float4 u0 = up[0], u1 = up[1];
    float cw[10];
    if (cb != nullptr) {
      const unsigned* cp = (const unsigned*)(cb + ((size_t)b * 1152 + n) * 10);
      unsigned c0 = cp[0], c1 = cp[1], c2 = cp[2], c3 = cp[3], c4 = cp[4];
      cw[0] = bf2f_lo(c0); cw[1] = bf2f_hi(c0);
      cw[2] = bf2f_lo(c1); cw[3] = bf2f_hi(c1);
      cw[4] = bf2f_lo(c2); cw[5] = bf2f_hi(c2);
      cw[6] = bf2f_lo(c3); cw[7] = bf2f_hi(c3);
      cw[8] = bf2f_lo(c4); cw[9] = bf2f_hi(c4);
    } else {
#pragma unroll
      for (int o = 0; o < 10; o++) cw[o] = 1.f;
    }
    const float4* wp = (const float4*)(Wt + (size_t)n * 1280 + e * 8);
#pragma unroll
    for (int o = 0; o < 10; o++) {
      float4 w0 = wp[o * 32], w1 = wp[o * 32 + 1];
      float uh = u0.x * w0.x + u0.y * w0.y + u0.z * w0.z + u0.w * w0.w +
                 u1.x * w1.x + u1.y * w1.y + u1.z * w1.z + u1.w * w1.w;
      acc[o] = fmaf(cw[o], uh, acc[o]);
    }
  }
  float* sp = spart + (size_t)nc * 81920 + (size_t)b * 160 + e;
#pragma unroll
  for (int o = 0; o < 10; o++) sp[o * 16] = acc[o];
}

// ---------------- v = squash(scale * sum_parts(s)); dst = v or dst += v ----------------
__global__ void squash_v_kernel(const float* __restrict__ spart,
                                float* __restrict__ dst, float prescale,
                                int accumulate) {
  int g = blockIdx.x * 256 + threadIdx.x;   // 5120 groups of 16
  if (g >= 5120) return;
  float r[16];
#pragma unroll
  for (int e = 0; e < 16; e++) r[e] = 0.f;
#pragma unroll
  for (int p = 0; p < 8; p++) {
    const float4* sp = (const float4*)(spart + (size_t)p * 81920 + (size_t)g * 16);
#pragma unroll
    for (int q = 0; q < 4; q++) {
      float4 f4 = sp[q];
      r[4 * q] += f4.x; r[4 * q + 1] += f4.y; r[4 * q + 2] += f4.z; r[4 * q + 3] += f4.w;
    }
  }
  float sn = 0.f;
#pragma unroll
  for (int e = 0; e < 16; e++) { r[e] *= prescale; sn += r[e] * r[e]; }
  float scale = sn / (1.f + sn) / (sqrtf(sn) + 1e-6f);
  float* q = dst + (size_t)g * 16;
#pragma unroll
  for (int e = 0; e < 16; e++) {
    float val = r[e] * scale;
    q[e] = accumulate ? (q[e] + val) : val;
  }
}

// ---------------- logits + softmax -> cb (bf16) ----------------
// grid 1152 (n), 128 threads, 4 b per thread.
__global__ __launch_bounds__(128) void logits_c_kernel(
    const float* __restrict__ u, const float* __restrict__ Wt,
    const float* __restrict__ vsum, short* __restrict__ cb) {
  __shared__ float Wl[1280];   // Wt[n]: [o][e][d]
  int n = blockIdx.x;
  int t = threadIdx.x;
  for (int i = t; i < 1280; i += 128) Wl[i] = Wt[(size_t)n * 1280 + i];
  __syncthreads();
  float u8[4][8];
#pragma unroll
  for (int k = 0; k < 4; k++) {
    int b = t + 128 * k;
    const float4* up = (const float4*)(u + ((size_t)b * 1152 + n) * 8);
    float4 a = up[0], c = up[1];
    u8[k][0] = a.x; u8[k][1] = a.y; u8[k][2] = a.z; u8[k][3] = a.w;
    u8[k][4] = c.x; u8[k][5] = c.y; u8[k][6] = c.z; u8[k][7] = c.w;
  }
  float dots[4][10];
#pragma unroll 1
  for (int o = 0; o < 10; o++) {
    float4 vs[4][4];
#pragma unroll
    for (int k = 0; k < 4; k++) {
      const float4* vp = (const float4*)(vsum + (size_t)(t + 128 * k) * 160 + o * 16);
#pragma unroll
      for (int q = 0; q < 4; q++) vs[k][q] = vp[q];
    }
    float d0 = 0.f, d1 = 0.f, d2 = 0.f, d3 = 0.f;
#pragma unroll
    for (int e = 0; e < 16; e++) {
      const float4* wp = (const float4*)&Wl[o * 128 + e * 8];
      float4 w0 = wp[0], w1 = wp[1];
      float vse0 = ((const float*)&vs[0][e >> 2])[e & 3];
      float vse1 = ((const float*)&vs[1][e >> 2])[e & 3];
      float vse2 = ((const float*)&vs[2][e >> 2])[e & 3];
      float vse3 = ((const float*)&vs[3][e >> 2])[e & 3];
      float uh0 = u8[0][0]*w0.x + u8[0][1]*w0.y + u8[0][2]*w0.z + u8[0][3]*w0.w +
                  u8[0][4]*w1.x + u8[0][5]*w1.y + u8[0][6]*w1.z + u8[0][7]*w1.w;
      float uh1 = u8[1][0]*w0.x + u8[1][1]*w0.y + u8[1][2]*w0.z + u8[1][3]*w0.w +
                  u8[1][4]*w1.x + u8[1][5]*w1.y + u8[1][6]*w1.z + u8[1][7]*w1.w;
      float uh2 = u8[2][0]*w0.x + u8[2][1]*w0.y + u8[2][2]*w0.z + u8[2][3]*w0.w +
                  u8[2][4]*w1.x + u8[2][5]*w1.y + u8[2][6]*w1.z + u8[2][7]*w1.w;
      float uh3 = u8[3][0]*w0.x + u8[3][1]*w0.y + u8[3][2]*w0.z + u8[3][3]*w0.w +
                  u8[3][4]*w1.x + u8[3][5]*w1.y + u8[3][6]*w1.z + u8[3][7]*w1.w;
      d0 = fmaf(uh0, vse0, d0); d1 = fmaf(uh1, vse1, d1);
      d2 = fmaf(uh2, vse2, d2); d3 = fmaf(uh3, vse3, d3);
    }
    dots[0][o] = d0; dots[1][o] = d1; dots[2][o] = d2; dots[3][o] = d3;
  }
#pragma unroll
  for (int k = 0; k < 4; k++) {
    int b = t + 128 * k;
    float m = dots[k][0];
#pragma unroll
    for (int o = 1; o < 10; o++) m = fmaxf(m, dots[k][o]);
    float sum = 0.f;
#pragma unroll
    for (int o = 0; o < 10; o++) { dots[k][o] = expf(dots[k][o] - m); sum += dots[k][o]; }
    float inv = 1.f / sum;
    unsigned* cp = (unsigned*)(cb + ((size_t)b * 1152 + n) * 10);
#pragma unroll
    for (int q = 0; q < 5; q++) {
      unsigned lo = (unsigned)(unsigned short)f2bf(dots[k][2 * q] * inv);
      unsigned hi = (unsigned)(unsigned short)f2bf(dots[k][2 * q + 1] * inv);
      cp[q] = lo | (hi << 16);
    }
  }
}

extern "C" void kernel_launch(void* const* d_in, const int* in_sizes, int n_in,
                              void* d_out, int out_size, void* d_ws, size_t ws_size,
                              hipStream_t stream) {
  const float* x   = (const float*)d_in[0];
  const float* w1  = (const float*)d_in[1];
  const float* b1v = (const float*)d_in[2];
  const float* w2  = (const float*)d_in[3];
  const float* b2v = (const float*)d_in[4];
  const float* W   = (const float*)d_in[5];
  float* out = (float*)d_out;

  char* ws = (char*)d_ws;
  float* u     = (float*)(ws + OFF_U);
  short* w2b   = (short*)(ws + OFF_A);      // conv phase
  short* cb    = (short*)(ws + OFF_A);      // routing phase (aliases w2b)
  float* Wt    = (float*)(ws + OFF_WT);
  float* spart = (float*)(ws + OFF_SPART);
  float* vsum  = (float*)(ws + OFF_VSUM);

  transpose_w2b_kernel<<<1024, 256, 0, stream>>>(w2, w2b);
  prep_wt_kernel<<<5760, 256, 0, stream>>>(W, Wt);
  conv_fused_kernel<<<256, 256, 0, stream>>>(x, w1, b1v, w2b, b2v, u);
  squash_u_kernel<<<2304, 256, 0, stream>>>(u);

  // iter 0: uniform c -> s0; vsum = v0
  s_part_kernel<<<dim3(32, 8), 256, 0, stream>>>(u, Wt, nullptr, spart);
  squash_v_kernel<<<20, 256, 0, stream>>>(spart, vsum, 0.1f, 0);
  // iter 1
  logits_c_kernel<<<1152, 128, 0, stream>>>(u, Wt, vsum, cb);
  s_part_kernel<<<dim3(32, 8), 256, 0, stream>>>(u, Wt, cb, spart);
  squash_v_kernel<<<20, 256, 0, stream>>>(spart, vsum, 1.0f, 1);
  // iter 2 -> output
  logits_c_kernel<<<1152, 128, 0, stream>>>(u, Wt, vsum, cb);
  s_part_kernel<<<dim3(32, 8), 256, 0, stream>>>(u, Wt, cb, spart);
  squash_v_kernel<<<20, 256, 0, stream>>>(spart, out, 1.0f, 0);
}